// Round 4
// baseline (122.891 us; speedup 1.0000x reference)
//
#include <hip/hip_runtime.h>
#include <hip/hip_bf16.h>

#define NN 100000   // nodes
#define H  256      // feature dim
#define NE 300000   // edges
#define KOUT 512    // y row length (u | v)
#define MT  782     // ceil(NN/128)

typedef __attribute__((ext_vector_type(8))) short short8;
typedef __attribute__((ext_vector_type(8))) unsigned short ushort8v;
typedef __attribute__((ext_vector_type(4))) float f32x4;

__device__ __forceinline__ unsigned short f2bf(float f) {
    unsigned int u = __float_as_uint(f);
    u += 0x7FFFu + ((u >> 16) & 1u);   // RNE
    return (unsigned short)(u >> 16);
}
__device__ __forceinline__ float bf2f(unsigned short h) {
    return __uint_as_float(((unsigned int)h) << 16);
}
// byte offset into a [rows][64] bf16 tile image (128B rows), XOR-swizzled
__device__ __forceinline__ int swz(int row, int coloff) {
    return row * 128 + (coloff ^ ((row & 7) << 4));
}
// async global->LDS, 16B per lane; LDS dest is wave-uniform base + lane*16
__device__ __forceinline__ void gload16(const void* g, void* l) {
    __builtin_amdgcn_global_load_lds((const __attribute__((address_space(1))) void*)g,
                                     (__attribute__((address_space(3))) void*)l,
                                     16, 0, 0);
}

// ---------------- W-prep: W1 (fp32 [512][256]) -> 16 pre-swizzled bf16 tiles.
// Tile index t = ks*4 + nt (K-step major, so one K-step's 4 tiles = 64KB linear).
// Tile image: [128 n][64 k] bf16, granule (n, kz-block) at byte swz(n, kz*2).
// Wcat[k][j]: j<256 -> W1[k][j]; j>=256 -> W1[k+256][j-256]; j = nt*128+n, k = ks*64+kz.
__global__ __launch_bounds__(256) void wprep(const float* __restrict__ W1,
                                             unsigned short* __restrict__ wsB) {
    int gtid = blockIdx.x * 256 + threadIdx.x;   // 16384 threads (64 blocks)
    int t  = gtid >> 10;          // 0..15 = ks*4+nt
    int kg = (gtid >> 7) & 7;     // 8-k group
    int n  = gtid & 127;
    int ks = t >> 2, nt = t & 3;
    int krow0 = ks * 64 + kg * 8 + ((nt >= 2) ? 256 : 0);
    int col = (nt & 1) * 128 + n;
    const float* src = W1 + (size_t)krow0 * 256 + col;
    ushort8v p;
    #pragma unroll
    for (int i = 0; i < 8; ++i) p[i] = f2bf(src[(size_t)i * 256]);
    *(ushort8v*)((char*)(wsB + t * 8192) + swz(n, kg * 16)) = p;
}

// ---------------- Fused GEMM: y[node][0:512] = x[node][:] @ Wcat. BM=128, BN=512, BK=64.
// 1024 threads = 16 waves (2 m-rows x 8 n-cols of 64x64 wave tiles).
// A: reg-staged fp32->bf16 (each x element converted exactly once), swizzled ds_write.
// B: global_load_lds from pre-swizzled wsB (one 64KB linear copy per K-step).
// MFMA with swapped operands -> transposed fragments -> packed 8B y stores.
__global__ __launch_bounds__(1024, 4) void gemm_f(const float* __restrict__ x,
                                                  const unsigned short* __restrict__ wsB,
                                                  unsigned short* __restrict__ y) {
    __shared__ unsigned short Al[8192];    // 16KB  [128 m][64 k] swizzled
    __shared__ unsigned short Bl[32768];   // 64KB  4 subtiles of [128 n][64 k] swizzled
    const int tid = threadIdx.x;
    const int m0 = (int)blockIdx.x * 128;
    const int lane = tid & 63, wid = tid >> 6;
    const int wm = (wid >> 3) * 64;        // 0 or 64
    const int wn = (wid & 7) * 64;         // 0..448
    const int lr = lane & 15, lk = lane >> 4;

    // A staging: thread -> (row ar, 8-float granule acg)
    const int ar = tid >> 3, acg = tid & 7;
    int node_s = m0 + ar; if (node_s > NN - 1) node_s = NN - 1;
    const float* xs = x + (size_t)node_s * H + acg * 8;

    // B staging: 16 waves x 4KB = 64KB linear copy
    const char* bs = (const char*)wsB + wid * 4096 + lane * 16;
    char* bd = (char*)Bl + wid * 4096;

    float4 p0, p1;
    f32x4 acc[4][4] = {};   // acc[ni][mi] — transposed tile (features x nodes)

    // prologue: A loads for ks=0
    p0 = *(const float4*)(xs);
    p1 = *(const float4*)(xs + 4);

    #pragma unroll
    for (int ks = 0; ks < 4; ++ks) {
        if (ks) __syncthreads();           // prev tile fully consumed
        // B: issue async copies first (fly under the A convert)
        #pragma unroll
        for (int i = 0; i < 4; ++i)
            gload16(bs + ks * 65536 + i * 1024, bd + i * 1024);
        // A: convert + swizzled LDS write
        {
            ushort8v q;
            q[0] = f2bf(p0.x); q[1] = f2bf(p0.y); q[2] = f2bf(p0.z); q[3] = f2bf(p0.w);
            q[4] = f2bf(p1.x); q[5] = f2bf(p1.y); q[6] = f2bf(p1.z); q[7] = f2bf(p1.w);
            *(ushort8v*)((char*)Al + swz(ar, acg * 16)) = q;
        }
        __syncthreads();                   // drains vmcnt+lgkm: Al/Bl ready
        if (ks < 3) {                      // prefetch next A under MFMA
            p0 = *(const float4*)(xs + (ks + 1) * 64);
            p1 = *(const float4*)(xs + (ks + 1) * 64 + 4);
        }
        #pragma unroll
        for (int kk = 0; kk < 64; kk += 32) {
            const int coloff = kk * 2 + lk * 16;
            short8 a[4], b[4];
            #pragma unroll
            for (int mi = 0; mi < 4; ++mi)
                a[mi] = *(const short8*)((const char*)Al + swz(wm + mi * 16 + lr, coloff));
            #pragma unroll
            for (int ni = 0; ni < 4; ++ni) {
                const int f = wn + ni * 16 + lr;
                b[ni] = *(const short8*)((const char*)Bl + (f >> 7) * 16384 + swz(f & 127, coloff));
            }
            #pragma unroll
            for (int ni = 0; ni < 4; ++ni)
                #pragma unroll
                for (int mi = 0; mi < 4; ++mi)
                    acc[ni][mi] = __builtin_amdgcn_mfma_f32_16x16x32_bf16(b[ni], a[mi], acc[ni][mi], 0, 0, 0);
        }
    }
    // epilogue: transposed D — lane holds 4 consecutive FEATURES (lk*4+r) of one node (lr)
    #pragma unroll
    for (int mi = 0; mi < 4; ++mi) {
        const int node = m0 + wm + mi * 16 + lr;
        if (node < NN) {
            #pragma unroll
            for (int ni = 0; ni < 4; ++ni) {
                const int feat = wn + ni * 16 + lk * 4;
                ushort4 u;
                u.x = f2bf(acc[ni][mi][0]);
                u.y = f2bf(acc[ni][mi][1]);
                u.z = f2bf(acc[ni][mi][2]);
                u.w = f2bf(acc[ni][mi][3]);
                *(ushort4*)(y + (size_t)node * KOUT + feat) = u;
            }
        }
    }
}

// ---------------- Phase 2: half-wave per edge, ushort8 gathers
__global__ __launch_bounds__(256) void edge_v2(const unsigned short* __restrict__ y,
                                               const int* __restrict__ ei,
                                               const float* __restrict__ b1,
                                               const float* __restrict__ W2,
                                               const float* __restrict__ b2,
                                               float* __restrict__ out) {
    const int tid = threadIdx.x;
    const int l32 = tid & 31;
    const int ghw = ((int)(blockIdx.x * blockDim.x) + tid) >> 5;
    const int nhw = ((int)(gridDim.x * blockDim.x)) >> 5;
    const int j = l32 * 8;
    const float4 b01 = *(const float4*)(b1 + j);
    const float4 b23 = *(const float4*)(b1 + j + 4);
    const float4 w01 = *(const float4*)(W2 + j);
    const float4 w23 = *(const float4*)(W2 + j + 4);
    const float bb = b2[0];
    #pragma unroll 2
    for (int e = ghw; e < NE; e += nhw) {
        int s = ei[e], d = ei[NE + e];
        s = s < 0 ? 0 : (s > NN - 1 ? NN - 1 : s);
        d = d < 0 ? 0 : (d > NN - 1 ? NN - 1 : d);
        ushort8v us = *(const ushort8v*)(y + (size_t)s * KOUT + j);
        ushort8v ud = *(const ushort8v*)(y + (size_t)d * KOUT + 256 + j);
        float acc;
        acc  = fmaxf(bf2f(us[0]) + bf2f(ud[0]) + b01.x, 0.f) * w01.x;
        acc += fmaxf(bf2f(us[1]) + bf2f(ud[1]) + b01.y, 0.f) * w01.y;
        acc += fmaxf(bf2f(us[2]) + bf2f(ud[2]) + b01.z, 0.f) * w01.z;
        acc += fmaxf(bf2f(us[3]) + bf2f(ud[3]) + b01.w, 0.f) * w01.w;
        acc += fmaxf(bf2f(us[4]) + bf2f(ud[4]) + b23.x, 0.f) * w23.x;
        acc += fmaxf(bf2f(us[5]) + bf2f(ud[5]) + b23.y, 0.f) * w23.y;
        acc += fmaxf(bf2f(us[6]) + bf2f(ud[6]) + b23.z, 0.f) * w23.z;
        acc += fmaxf(bf2f(us[7]) + bf2f(ud[7]) + b23.w, 0.f) * w23.w;
        #pragma unroll
        for (int off = 16; off > 0; off >>= 1) acc += __shfl_xor(acc, off, 64);
        if (l32 == 0) out[e] = acc + bb;
    }
}

// ---------------- Fallback (ws too small): fused wave-per-edge, fp32. Slow but correct.
__global__ __launch_bounds__(256) void fused_fallback(const float* __restrict__ x,
                                                      const int* __restrict__ ei,
                                                      const float* __restrict__ W1,
                                                      const float* __restrict__ b1,
                                                      const float* __restrict__ W2,
                                                      const float* __restrict__ b2,
                                                      float* __restrict__ out) {
    __shared__ float xsh[4][512];
    const int lane = threadIdx.x & 63;
    const int wl = threadIdx.x >> 6;
    const int gw = (blockIdx.x * blockDim.x + threadIdx.x) >> 6;
    const int nw = (gridDim.x * blockDim.x) >> 6;
    const int j = lane * 4;
    const float4 bv = *(const float4*)(b1 + j);
    const float4 wv = *(const float4*)(W2 + j);
    const float bb = b2[0];
    for (int e = gw; e < NE; e += nw) {
        int s = ei[e], d = ei[NE + e];
        s = min(max(s, 0), NN - 1);
        d = min(max(d, 0), NN - 1);
        __threadfence_block();
        #pragma unroll
        for (int i = 0; i < 4; ++i) {
            xsh[wl][i * 64 + lane]       = x[(size_t)s * H + i * 64 + lane];
            xsh[wl][256 + i * 64 + lane] = x[(size_t)d * H + i * 64 + lane];
        }
        __threadfence_block();
        float h0 = bv.x, h1 = bv.y, h2 = bv.z, h3 = bv.w;
        for (int k = 0; k < 256; ++k) {
            float xa = xsh[wl][k], xb2 = xsh[wl][256 + k];
            float4 wa = *(const float4*)(W1 + (size_t)k * 256 + j);
            float4 wb = *(const float4*)(W1 + (size_t)(k + 256) * 256 + j);
            h0 += xa * wa.x + xb2 * wb.x;
            h1 += xa * wa.y + xb2 * wb.y;
            h2 += xa * wa.z + xb2 * wb.z;
            h3 += xa * wa.w + xb2 * wb.w;
        }
        float acc = fmaxf(h0, 0.f) * wv.x + fmaxf(h1, 0.f) * wv.y +
                    fmaxf(h2, 0.f) * wv.z + fmaxf(h3, 0.f) * wv.w;
        #pragma unroll
        for (int off = 32; off > 0; off >>= 1) acc += __shfl_xor(acc, off, 64);
        if (lane == 0) out[e] = acc + bb;
    }
}

extern "C" void kernel_launch(void* const* d_in, const int* in_sizes, int n_in,
                              void* d_out, int out_size, void* d_ws, size_t ws_size,
                              hipStream_t stream) {
    const float* x  = (const float*)d_in[0];
    const int*   ei = (const int*)d_in[1];
    const float* W1 = (const float*)d_in[2];
    const float* b1 = (const float*)d_in[3];
    const float* W2 = (const float*)d_in[4];
    const float* b2 = (const float*)d_in[5];
    float* out = (float*)d_out;

    const size_t ybytes = (size_t)NN * KOUT * sizeof(unsigned short);  // 102.4 MB
    const size_t wbytes = 16 * 8192 * sizeof(unsigned short);          // 256 KB

    if (ws_size >= ybytes + wbytes) {
        unsigned short* yb = (unsigned short*)d_ws;
        unsigned short* wb = (unsigned short*)((char*)d_ws + ybytes);
        wprep<<<dim3(64), dim3(256), 0, stream>>>(W1, wb);
        gemm_f<<<dim3(MT), dim3(1024), 0, stream>>>(x, wb, yb);
        edge_v2<<<dim3(2048), dim3(256), 0, stream>>>(yb, ei, b1, W2, b2, out);
    } else {
        fused_fallback<<<dim3(2048), dim3(256), 0, stream>>>(x, ei, W1, b1, W2, b2, out);
    }
}